// Round 3
// baseline (765.109 us; speedup 1.0000x reference)
//
#include <hip/hip_runtime.h>

#ifndef __has_builtin
#define __has_builtin(x) 0
#endif

typedef float v2f __attribute__((ext_vector_type(2)));

__device__ __forceinline__ float fexp2(float x) {
#if __has_builtin(__builtin_amdgcn_exp2f)
    return __builtin_amdgcn_exp2f(x);   // v_exp_f32 (2^x)
#else
    return exp2f(x);
#endif
}
__device__ __forceinline__ float flog2(float x) {
#if __has_builtin(__builtin_amdgcn_logf)
    return __builtin_amdgcn_logf(x);    // v_log_f32 (log2 x)
#else
    return log2f(x);
#endif
}
__device__ __forceinline__ float frcp(float x) {
#if __has_builtin(__builtin_amdgcn_rcpf)
    return __builtin_amdgcn_rcpf(x);    // v_rcp_f32 (approx; Sinkhorn self-corrects)
#else
    return 1.0f / x;
#endif
}

// ---- cross-lane helpers (round-1 proven set: DPP + ds_swizzle + shfl) -------
#define DPP_QX1  0xB1   // quad_perm [1,0,3,2] : lane ^ 1
#define DPP_QX2  0x4E   // quad_perm [2,3,0,1] : lane ^ 2
#define DPP_ROR4 0x124  // row_ror:4 (with ror8: sums full stride-4 class in 16)
#define DPP_ROR8 0x128  // row_ror:8
#define DPP_RHM  0x141  // row_half_mirror: i <-> 7-i within each 8-lane half

template<int CTRL>
__device__ __forceinline__ float dppf(float x) {
    return __int_as_float(__builtin_amdgcn_update_dpp(
        0, __float_as_int(x), CTRL, 0xF, 0xF, true));
}
// lane ^ 16 (ds_swizzle bitmode; xor stays within each 32-lane half)
__device__ __forceinline__ float swzx16(float x) {
    return __int_as_float(__builtin_amdgcn_ds_swizzle(__float_as_int(x), 0x401F));
}

#define NMAXN 128
#define DD    64
#define MAX_ITERS 500
#define KLOG  12            // log-domain warm-up iterations

// -1e5 * log2(e)  (NEG surrogate in log2 domain)
#define NEG2  (-144269.50408889634f)
// -(log2(e) / eps), eps = 1e-3 : logK2 = M * LKSC
#define LKSC  (-1442.6950408889634f)
// -(eps * ln2) : out = acc * OUTSC
#define OUTSC (-6.931471805599453e-4f)

// 1024 threads = 16 waves. Each wave owns 8 columns {4w+cg, 4w+cg+64} over all
// 128 rows -> column reductions stay fully in-wave (2 barriers/iter preserved).
// Each thread: 8 rows (rg+16r) x 2 cols -> v2f tile, half the round-1 state.
struct SmemStage {
    float A[NMAXN * 33];   // set1 chunk [128][32] padded
    float B[NMAXN * 33];   // set2 chunk
    float nA[NMAXN];       // row norms set1
    float nB[NMAXN];       // row norms set2
};
struct SmemSink {
    float pm[NMAXN * 17];   // log-phase row-max partials  [row*17 + w], w=0..15
    float ps[NMAXN * 17];   // log-phase row-sum partials
    float pmul[NMAXN * 17]; // mul-phase row-sum partials
    float ug[NMAXN];        // u (phase 1) / g (phase 2)
};
union SmemU {
    SmemStage st;
    SmemSink  sk;
};

__global__ __launch_bounds__(1024, 8)
void wasserstein_kernel(const float* __restrict__ x1, const float* __restrict__ x2,
                        const int* __restrict__ sz1, const int* __restrict__ sz2,
                        float* __restrict__ out)
{
    __shared__ SmemU  sm;
    __shared__ int    soff[32];
    __shared__ float  swred[16];

    const int b    = blockIdx.x;
    const int tid  = threadIdx.x;
    const int w    = tid >> 6;        // wave 0..15
    const int lane = tid & 63;
    const int rg   = lane >> 4;       // unused placeholder (recomputed below)
    (void)rg;
    const int rg4  = lane >> 2;       // 0..15 : rows rg4 + 16*r (r = 0..7)
    const int cg   = lane & 3;
    const int cw   = (w << 2) | cg;   // col base 0..63; cols {cw, cw+64}

    const int crow = tid >> 3;        // combine row 0..127 (8 lanes per row)
    const int q8   = tid & 7;

    // ---- exclusive prefix sums of sizes (one element per thread) ----
    int a1 = (tid < b) ? sz1[tid] : 0;
    int a2 = (tid < b) ? sz2[tid] : 0;
#pragma unroll
    for (int d = 1; d < 64; d <<= 1) {
        a1 += __shfl_xor(a1, d);
        a2 += __shfl_xor(a2, d);
    }
    if (lane == 0) { soff[w] = a1; soff[16 + w] = a2; }
    if (tid < NMAXN) { sm.st.nA[tid] = 0.f; sm.st.nB[tid] = 0.f; }
    __syncthreads();
    int off1 = 0, off2 = 0;
#pragma unroll
    for (int i = 0; i < 16; ++i) { off1 += soff[i]; off2 += soff[16 + i]; }
    const int n1 = sz1[b];
    const int n2 = sz2[b];

    // ---- stage sets in D-chunks of 32, accumulate dots + norms ----
    v2f lk2[8];   // [r] over 2 cols; starts as dot acc, becomes logK2
#pragma unroll
    for (int r = 0; r < 8; ++r) { lk2[r].x = 0.f; lk2[r].y = 0.f; }

    const int srow = tid >> 3;  // 0..127
    const int sq   = tid & 7;   // float4 slice of the 32-col chunk

    for (int ch = 0; ch < 2; ++ch) {
        const float* p1 = x1 + (size_t)(off1 + srow) * DD + ch * 32 + sq * 4;
        const float* p2 = x2 + (size_t)(off2 + srow) * DD + ch * 32 + sq * 4;
        const bool ok1 = srow < n1;
        const bool ok2 = srow < n2;
        float4 t1 = ok1 ? *(const float4*)p1 : make_float4(0.f, 0.f, 0.f, 0.f);
        float4 t2 = ok2 ? *(const float4*)p2 : make_float4(0.f, 0.f, 0.f, 0.f);
        float va[4] = { t1.x, t1.y, t1.z, t1.w };
        float vb[4] = { t2.x, t2.y, t2.z, t2.w };
        float s1 = 0.f, s2v = 0.f;
#pragma unroll
        for (int j = 0; j < 4; ++j) {
            sm.st.A[srow * 33 + sq * 4 + j] = va[j];
            sm.st.B[srow * 33 + sq * 4 + j] = vb[j];
            s1  += va[j] * va[j];
            s2v += vb[j] * vb[j];
        }
        // reduce over the 8 lanes sharing a row: x^1, x^2, then half-mirror
        s1  += dppf<DPP_QX1>(s1);  s1  += dppf<DPP_QX2>(s1);  s1  += dppf<DPP_RHM>(s1);
        s2v += dppf<DPP_QX1>(s2v); s2v += dppf<DPP_QX2>(s2v); s2v += dppf<DPP_RHM>(s2v);
        if (sq == 0) { sm.st.nA[srow] += s1; sm.st.nB[srow] += s2v; }
        __syncthreads();
#pragma unroll 2
        for (int d = 0; d < 32; ++d) {
            float av[8];
#pragma unroll
            for (int r = 0; r < 8; ++r) av[r] = sm.st.A[(rg4 + 16*r) * 33 + d];
            v2f bv2;
            bv2.x = sm.st.B[(cw     ) * 33 + d];
            bv2.y = sm.st.B[(cw + 64) * 33 + d];
#pragma unroll
            for (int r = 0; r < 8; ++r)
                lk2[r] += bv2 * av[r];   // v_pk_fma_f32
        }
        __syncthreads();
    }

    // logK2 = -M*log2e/eps, M = ||a||^2 + ||b||^2 - 2ab (clamped >= 0)
    v2f lb2;
    const float lbv = flog2((float)n1) - flog2((float)n2);
    {
        v2f rn2;
        rn2.x = sm.st.nB[cw];
        rn2.y = sm.st.nB[cw + 64];
#pragma unroll
        for (int r = 0; r < 8; ++r) {
            float rn1 = sm.st.nA[rg4 + 16*r];
            v2f M2 = rn1 + rn2 - 2.f * lk2[r];
            lk2[r].x = fmaxf(M2.x, 0.f) * LKSC;
            lk2[r].y = fmaxf(M2.y, 0.f) * LKSC;
        }
        lb2.x = (cw      < n2) ? lbv : NEG2;
        lb2.y = (cw + 64 < n2) ? lbv : NEG2;
    }
    __syncthreads();   // retire staging view of the union

    const float lacrow = (crow < n1) ? 0.f : NEG2;

    float uloc[8];
    v2f vv;
#pragma unroll
    for (int r = 0; r < 8; ++r) uloc[r] = 0.f;

    // ================= Phase 1: KLOG log-domain iterations =================
    for (int k = 0; k < KLOG; ++k) {
        // column logsumexp over all 128 rows (in-thread r, then rg4 lane stages)
        float mx0 = lk2[0].x + uloc[0];
        float mx1 = lk2[0].y + uloc[0];
#pragma unroll
        for (int r = 1; r < 8; ++r) {
            mx0 = fmaxf(mx0, lk2[r].x + uloc[r]);
            mx1 = fmaxf(mx1, lk2[r].y + uloc[r]);
        }
        mx0 = fmaxf(mx0, dppf<DPP_ROR4>(mx0)); mx1 = fmaxf(mx1, dppf<DPP_ROR4>(mx1));
        mx0 = fmaxf(mx0, dppf<DPP_ROR8>(mx0)); mx1 = fmaxf(mx1, dppf<DPP_ROR8>(mx1));
        mx0 = fmaxf(mx0, swzx16(mx0));         mx1 = fmaxf(mx1, swzx16(mx1));
        mx0 = fmaxf(mx0, __shfl_xor(mx0, 32)); mx1 = fmaxf(mx1, __shfl_xor(mx1, 32));

        float sc0 = fexp2(lk2[0].x + uloc[0] - mx0);
        float sc1 = fexp2(lk2[0].y + uloc[0] - mx1);
#pragma unroll
        for (int r = 1; r < 8; ++r) {
            sc0 += fexp2(lk2[r].x + uloc[r] - mx0);
            sc1 += fexp2(lk2[r].y + uloc[r] - mx1);
        }
        sc0 += dppf<DPP_ROR4>(sc0); sc1 += dppf<DPP_ROR4>(sc1);
        sc0 += dppf<DPP_ROR8>(sc0); sc1 += dppf<DPP_ROR8>(sc1);
        sc0 += swzx16(sc0);         sc1 += swzx16(sc1);
        sc0 += __shfl_xor(sc0, 32); sc1 += __shfl_xor(sc1, 32);

        vv.x = lb2.x - (mx0 + flog2(sc0));
        vv.y = lb2.y - (mx1 + flog2(sc1));

        // row logsumexp partials: this wave's 8 cols (2 in-thread + cg stages)
#pragma unroll
        for (int r = 0; r < 8; ++r) {
            float mr = fmaxf(lk2[r].x + vv.x, lk2[r].y + vv.y);
            mr = fmaxf(mr, dppf<DPP_QX1>(mr));
            mr = fmaxf(mr, dppf<DPP_QX2>(mr));
            float sr = fexp2(lk2[r].x + vv.x - mr) + fexp2(lk2[r].y + vv.y - mr);
            sr += dppf<DPP_QX1>(sr);
            sr += dppf<DPP_QX2>(sr);
            if ((r & 3) == cg) {
                const int row = rg4 + 16*r;
                sm.sk.pm[row * 17 + w] = mr;
                sm.sk.ps[row * 17 + w] = sr;
            }
        }
        __syncthreads();                               // B1

        {   // combine: 8 lanes per row fold 16 (m,s) partials
            float m0 = sm.sk.pm[crow * 17 + 2*q8], m1 = sm.sk.pm[crow * 17 + 2*q8 + 1];
            float s0 = sm.sk.ps[crow * 17 + 2*q8], s1 = sm.sk.ps[crow * 17 + 2*q8 + 1];
            float m = fmaxf(m0, m1);
            float s = s0 * fexp2(m0 - m) + s1 * fexp2(m1 - m);
            float mo = dppf<DPP_QX1>(m), so = dppf<DPP_QX1>(s);
            float mm = fmaxf(m, mo);
            s = s * fexp2(m - mm) + so * fexp2(mo - mm); m = mm;
            mo = dppf<DPP_QX2>(m); so = dppf<DPP_QX2>(s);
            mm = fmaxf(m, mo);
            s = s * fexp2(m - mm) + so * fexp2(mo - mm); m = mm;
            mo = dppf<DPP_RHM>(m); so = dppf<DPP_RHM>(s);
            mm = fmaxf(m, mo);
            s = s * fexp2(m - mm) + so * fexp2(mo - mm); m = mm;
            if (q8 == 0) sm.sk.ug[crow] = lacrow - (m + flog2(s));
        }
        __syncthreads();                               // B2

#pragma unroll
        for (int r = 0; r < 8; ++r) uloc[r] = sm.sk.ug[rg4 + 16*r];
    }

    // ============== Transition: Q = exp2(lk + u + v) =======================
    v2f Q2[8];
#pragma unroll
    for (int r = 0; r < 8; ++r) {
        Q2[r].x = fexp2(lk2[r].x + uloc[r] + vv.x);
        Q2[r].y = fexp2(lk2[r].y + uloc[r] + vv.y);
    }

    const float bmulv = (float)n1 / (float)n2;   // beta for valid cols
    v2f fm2;
    fm2.x = (cw      < n2) ? bmulv : 0.f;
    fm2.y = (cw + 64 < n2) ? bmulv : 0.f;
    const float gmask = (crow < n1) ? 1.f : 0.f;

    float gl[8];
#pragma unroll
    for (int r = 0; r < 8; ++r) gl[r] = 1.f;

    // ============== Phase 2: multiplicative Sinkhorn (lazy g) ==============
    // col: s_c = sum_r g_r Q[r][c]; f_c = beta_c / s_c
    // row: Q *= f (fused), then t_r = sum_c Q[r][c]; g_r = alpha_r / t_r
    // plan = diag(g) Q; fold g in every 16 iters to bound Q's drift.
    for (int k = KLOG; k < MAX_ITERS; ++k) {
        // --- column sums (2 independent fma chains for ILP) ---
        v2f p0 = Q2[0] * gl[0];
        v2f p1 = Q2[1] * gl[1];
#pragma unroll
        for (int r = 2; r < 8; r += 2) {
            p0 += Q2[r  ] * gl[r  ];   // v_pk_fma_f32
            p1 += Q2[r+1] * gl[r+1];
        }
        v2f s2 = p0 + p1;
        float s0 = s2.x, s1 = s2.y;
        s0 += dppf<DPP_ROR4>(s0); s1 += dppf<DPP_ROR4>(s1);
        s0 += dppf<DPP_ROR8>(s0); s1 += dppf<DPP_ROR8>(s1);
        s0 += swzx16(s0);         s1 += swzx16(s1);
        s0 += __shfl_xor(s0, 32); s1 += __shfl_xor(s1, 32);
        v2f f2;
        f2.x = fm2.x * frcp(fmaxf(s0, 1e-37f));
        f2.y = fm2.y * frcp(fmaxf(s1, 1e-37f));

        // --- fused: Q *= f, then row partials from the updated Q ---
#pragma unroll
        for (int r = 0; r < 8; ++r) {
            Q2[r] *= f2;
            float t = Q2[r].x + Q2[r].y;
            t += dppf<DPP_QX1>(t);
            t += dppf<DPP_QX2>(t);
            if ((r & 3) == cg)
                sm.sk.pmul[(rg4 + 16*r) * 17 + w] = t;
        }
        __syncthreads();                               // B1

        {
            float t0 = sm.sk.pmul[crow * 17 + 2*q8];
            float t1 = sm.sk.pmul[crow * 17 + 2*q8 + 1];
            float t = t0 + t1;
            t += dppf<DPP_QX1>(t);
            t += dppf<DPP_QX2>(t);
            t += dppf<DPP_RHM>(t);
            float gg = gmask * frcp(fmaxf(t, 1e-37f));
            if (q8 == 0) sm.sk.ug[crow] = gg;
        }
        __syncthreads();                               // B2

#pragma unroll
        for (int r = 0; r < 8; ++r) gl[r] = sm.sk.ug[rg4 + 16*r];

        if ((k & 15) == 15) {   // fold pending row scale into Q (bounds drift)
#pragma unroll
            for (int r = 0; r < 8; ++r) {
                Q2[r] *= gl[r];
                gl[r] = 1.f;
            }
        }
    }

    // ---- epilogue: out_b = OUTSC * sum_ij lk_ij * (g_r Q_ij) ----
    v2f acc2; acc2.x = 0.f; acc2.y = 0.f;
#pragma unroll
    for (int r = 0; r < 8; ++r)
        acc2 += lk2[r] * (Q2[r] * gl[r]);
    float acc = acc2.x + acc2.y;
    acc += dppf<DPP_QX1>(acc);
    acc += dppf<DPP_QX2>(acc);
    acc += dppf<DPP_ROR4>(acc);
    acc += dppf<DPP_ROR8>(acc);
    acc += swzx16(acc);
    acc += __shfl_xor(acc, 32);
    if (lane == 0) swred[w] = acc;
    __syncthreads();
    if (tid == 0) {
        float s = 0.f;
#pragma unroll
        for (int i = 0; i < 16; ++i) s += swred[i];
        out[b] = s * OUTSC;
    }
}

extern "C" void kernel_launch(void* const* d_in, const int* in_sizes, int n_in,
                              void* d_out, int out_size, void* d_ws, size_t ws_size,
                              hipStream_t stream) {
    const float* x1  = (const float*)d_in[0];
    const float* x2  = (const float*)d_in[1];
    const int*   sz1 = (const int*)d_in[2];
    const int*   sz2 = (const int*)d_in[3];
    float* out = (float*)d_out;
    hipLaunchKernelGGL(wasserstein_kernel, dim3(512), dim3(1024), 0, stream,
                       x1, x2, sz1, sz2, out);
}

// Round 5
// 639.209 us; speedup vs baseline: 1.1970x; 1.1970x over previous
//
#include <hip/hip_runtime.h>

#ifndef __has_builtin
#define __has_builtin(x) 0
#endif

typedef float v2f __attribute__((ext_vector_type(2)));

__device__ __forceinline__ float fexp2(float x) {
#if __has_builtin(__builtin_amdgcn_exp2f)
    return __builtin_amdgcn_exp2f(x);   // v_exp_f32 (2^x)
#else
    return exp2f(x);
#endif
}
__device__ __forceinline__ float flog2(float x) {
#if __has_builtin(__builtin_amdgcn_logf)
    return __builtin_amdgcn_logf(x);    // v_log_f32 (log2 x)
#else
    return log2f(x);
#endif
}
__device__ __forceinline__ float frcp(float x) {
#if __has_builtin(__builtin_amdgcn_rcpf)
    return __builtin_amdgcn_rcpf(x);    // v_rcp_f32 (approx; Sinkhorn self-corrects)
#else
    return 1.0f / x;
#endif
}

// ---- cross-lane helpers (round-1 proven set: DPP + ds_swizzle + shfl) -------
#define DPP_QX1  0xB1   // quad_perm [1,0,3,2] : lane ^ 1
#define DPP_QX2  0x4E   // quad_perm [2,3,0,1] : lane ^ 2
#define DPP_ROR4 0x124  // row_ror:4 (with ror8: sums full stride-4 class in 16)
#define DPP_ROR8 0x128  // row_ror:8

template<int CTRL>
__device__ __forceinline__ float dppf(float x) {
    return __int_as_float(__builtin_amdgcn_update_dpp(
        0, __float_as_int(x), CTRL, 0xF, 0xF, true));
}
// lane ^ 16 (ds_swizzle bitmode; xor stays within each 32-lane half)
__device__ __forceinline__ float swzx16(float x) {
    return __int_as_float(__builtin_amdgcn_ds_swizzle(__float_as_int(x), 0x401F));
}

#define NMAXN 128
#define DD    64
#define MAX_ITERS 500
#define KLOG  12            // log-domain warm-up iterations

// -1e5 * log2(e)  (NEG surrogate in log2 domain)
#define NEG2  (-144269.50408889634f)
// -(log2(e) / eps), eps = 1e-3 : logK2 = M * LKSC
#define LKSC  (-1442.6950408889634f)
// -(eps * ln2) : out = acc * OUTSC
#define OUTSC (-6.931471805599453e-4f)

// scalar view of the packed lk tile (c = 0..3 -> pair c>>1, half c&1)
#define LK(r, c) (((c) & 1) ? lk2[r][(c) >> 1].y : lk2[r][(c) >> 1].x)

struct SmemStage {
    float A[NMAXN * 33];   // set1 chunk [128][32] padded
    float B[NMAXN * 33];   // set2 chunk
    float nA[NMAXN];       // row norms set1
    float nB[NMAXN];       // row norms set2
};
struct SmemSink {
    float2 plog[NMAXN * 10];  // log-phase partials: [row*10+w] -> (max,sum)
    float  ulog[NMAXN];       // log-phase u
    float  pmul[NMAXN * 10];  // mul-phase row-sum partials: [row*10+w]
    float  g[NMAXN];          // mul-phase row factors
};
union SmemU {
    SmemStage st;
    SmemSink  sk;
    // occupancy clamp: 60 KiB -> exactly 2 blocks/CU; 512 blocks = 512 slots.
    char force[61440];
};

// ================= Phase 2 (templated on NR = ceil(n1/16)) ==================
// Multiplicative Sinkhorn with lazy row factor g AND lazy column factor fc.
// Telescoping: fc_new = fc_old * (fm/(fc_old*S)) = fm/S, so the total pending
// column factor (since the last fold) is fm/S directly -- bounded, because S
// is the colsum of the recently-folded, plan-scale Q (round-1's empirical
// 16-iter drift bound). Both factors fold into Q every 16 iters.
// Rows r >= NR are exact zeros (u=NEG2 -> Q=0) and are skipped everywhere;
// their g comes from stale LDS but gmask=0 and the clamped rcp keep it 0.
template<int NR>
__device__ __forceinline__ float sink_mul(
    v2f (&lk2)[8][2], const float (&uloc)[8], const float (&v)[4],
    const float (&fm)[4], float gmask,
    SmemU& sm, int rg, int cg, int w, int crow, int q)
{
    // transition: Q = exp2(lk + u + v), constant between folds
    v2f Q2[NR][2];
#pragma unroll
    for (int r = 0; r < NR; ++r)
#pragma unroll
        for (int j = 0; j < 2; ++j) {
            Q2[r][j].x = fexp2(LK(r, 2*j    ) + uloc[r] + v[2*j    ]);
            Q2[r][j].y = fexp2(LK(r, 2*j + 1) + uloc[r] + v[2*j + 1]);
        }
    float gl[NR];
#pragma unroll
    for (int r = 0; r < NR; ++r) gl[r] = 1.f;
    v2f fc2[2];
    fc2[0].x = fc2[0].y = 0.f;
    fc2[1] = fc2[0];

    for (int k = KLOG; k < MAX_ITERS; ++k) {
        // --- col sums s_c = sum_r g_r Q_rc (2x2 independent fma chains) ---
        v2f p0 = Q2[0][0] * gl[0];
        v2f q0 = Q2[0][1] * gl[0];
        v2f p1; p1.x = 0.f; p1.y = 0.f;
        v2f q1 = p1;
        if constexpr (NR > 1) { p1 = Q2[1][0] * gl[1]; q1 = Q2[1][1] * gl[1]; }
#pragma unroll
        for (int r = 2; r < NR; ++r) {
            if ((r & 1) == 0) { p0 += Q2[r][0] * gl[r]; q0 += Q2[r][1] * gl[r]; }
            else              { p1 += Q2[r][0] * gl[r]; q1 += Q2[r][1] * gl[r]; }
        }
        v2f s20 = p0 + p1;
        v2f s21 = q0 + q1;
        float s[4] = { s20.x, s20.y, s21.x, s21.y };
#pragma unroll
        for (int c = 0; c < 4; ++c) s[c] += dppf<DPP_ROR4>(s[c]);
#pragma unroll
        for (int c = 0; c < 4; ++c) s[c] += dppf<DPP_ROR8>(s[c]);
#pragma unroll
        for (int c = 0; c < 4; ++c) s[c] += swzx16(s[c]);
#pragma unroll
        for (int c = 0; c < 4; ++c) s[c] += __shfl_xor(s[c], 32);
        // pending column factor = fm / S (total since last fold)
        fc2[0].x = fm[0] * frcp(fmaxf(s[0], 1e-37f));
        fc2[0].y = fm[1] * frcp(fmaxf(s[1], 1e-37f));
        fc2[1].x = fm[2] * frcp(fmaxf(s[2], 1e-37f));
        fc2[1].y = fm[3] * frcp(fmaxf(s[3], 1e-37f));

        // --- row sums t_r = sum_c Q_rc fc_c (Q read-only) ---
#pragma unroll
        for (int r = 0; r < NR; ++r) {
            v2f t2 = Q2[r][0] * fc2[0];
            t2 += Q2[r][1] * fc2[1];     // v_pk_fma_f32
            float t = t2.x + t2.y;
            t += dppf<DPP_QX1>(t);
            t += dppf<DPP_QX2>(t);
            if ((r & 3) == cg)
                sm.sk.pmul[(rg + 16*r) * 10 + w] = t;
        }
        __syncthreads();                               // B1

        {   // cooperative combine: 4 lanes per row fold 8 partials
            float2 t2r = *(const float2*)&sm.sk.pmul[crow * 10 + 2 * q];
            float t = t2r.x + t2r.y;
            t += dppf<DPP_QX1>(t);
            t += dppf<DPP_QX2>(t);
            float gg = gmask * frcp(fmaxf(t, 1e-37f));
            if (q == 0) sm.sk.g[crow] = gg;
        }
        __syncthreads();                               // B2

#pragma unroll
        for (int r = 0; r < NR; ++r) gl[r] = sm.sk.g[rg + 16*r];

        // fold both pending factors into Q (bounds drift; k=499 is NOT a fold
        // iteration with these constants, so epilogue factors stay pending)
        if ((k & 15) == 15) {
#pragma unroll
            for (int r = 0; r < NR; ++r) {
                Q2[r][0] *= fc2[0] * gl[r];
                Q2[r][1] *= fc2[1] * gl[r];
                gl[r] = 1.f;
            }
        }
    }

    // ---- epilogue accumulate: sum_ij lk_ij * (g_r Q_ij fc_c) ----
    v2f acc2; acc2.x = 0.f; acc2.y = 0.f;
#pragma unroll
    for (int r = 0; r < NR; ++r)
#pragma unroll
        for (int j = 0; j < 2; ++j)
            acc2 += lk2[r][j] * (Q2[r][j] * (fc2[j] * gl[r]));
    return acc2.x + acc2.y;
}

__global__ __launch_bounds__(512, 4)
void wasserstein_kernel(const float* __restrict__ x1, const float* __restrict__ x2,
                        const int* __restrict__ sz1, const int* __restrict__ sz2,
                        float* __restrict__ out)
{
    __shared__ SmemU  sm;
    __shared__ int    soff[16];
    __shared__ float  swred[8];

    const int b    = blockIdx.x;
    const int tid  = threadIdx.x;
    const int w    = tid >> 6;        // wave 0..7
    const int lane = tid & 63;
    const int rg   = lane >> 2;       // 0..15 : rows rg + 16*r   (r = 0..7)
    const int cg   = lane & 3;        // with w: cols (w*4+cg) + 32*c (c = 0..3)
    const int cb32 = (w << 2) | cg;   // 0..31

    // ---- exclusive prefix sums of sizes (512 threads: one element each) ----
    int a1 = (tid < b) ? sz1[tid] : 0;
    int a2 = (tid < b) ? sz2[tid] : 0;
#pragma unroll
    for (int d = 1; d < 64; d <<= 1) {
        a1 += __shfl_xor(a1, d);
        a2 += __shfl_xor(a2, d);
    }
    if (lane == 0) { soff[w] = a1; soff[8 + w] = a2; }
    if (tid < NMAXN) { sm.st.nA[tid] = 0.f; sm.st.nB[tid] = 0.f; }
    __syncthreads();
    int off1 = 0, off2 = 0;
#pragma unroll
    for (int i = 0; i < 8; ++i) { off1 += soff[i]; off2 += soff[8 + i]; }
    const int n1 = sz1[b];
    const int n2 = sz2[b];

    // ---- stage sets in D-chunks of 32, accumulate dots + norms ----
    v2f lk2[8][2];   // packed over col pairs; starts as dot acc, becomes logK2
#pragma unroll
    for (int r = 0; r < 8; ++r)
#pragma unroll
        for (int j = 0; j < 2; ++j) { lk2[r][j].x = 0.f; lk2[r][j].y = 0.f; }

    const int srow = tid >> 2;  // 0..127
    const int sq   = tid & 3;   // 8-float slice of the 32-col chunk

    for (int ch = 0; ch < 2; ++ch) {
        const float* p1 = x1 + (size_t)(off1 + srow) * DD + ch * 32 + sq * 8;
        const float* p2 = x2 + (size_t)(off2 + srow) * DD + ch * 32 + sq * 8;
        const bool ok1 = srow < n1;
        const bool ok2 = srow < n2;
        float va[8], vb[8];
#pragma unroll
        for (int qq = 0; qq < 2; ++qq) {
            float4 t1 = ok1 ? ((const float4*)p1)[qq] : make_float4(0.f, 0.f, 0.f, 0.f);
            float4 t2 = ok2 ? ((const float4*)p2)[qq] : make_float4(0.f, 0.f, 0.f, 0.f);
            va[4*qq+0] = t1.x; va[4*qq+1] = t1.y; va[4*qq+2] = t1.z; va[4*qq+3] = t1.w;
            vb[4*qq+0] = t2.x; vb[4*qq+1] = t2.y; vb[4*qq+2] = t2.z; vb[4*qq+3] = t2.w;
        }
        float s1 = 0.f, s2v = 0.f;
#pragma unroll
        for (int j = 0; j < 8; ++j) {
            sm.st.A[srow * 33 + sq * 8 + j] = va[j];
            sm.st.B[srow * 33 + sq * 8 + j] = vb[j];
            s1  += va[j] * va[j];
            s2v += vb[j] * vb[j];
        }
        s1  += dppf<DPP_QX1>(s1);  s1  += dppf<DPP_QX2>(s1);
        s2v += dppf<DPP_QX1>(s2v); s2v += dppf<DPP_QX2>(s2v);
        if (sq == 0) { sm.st.nA[srow] += s1; sm.st.nB[srow] += s2v; }
        __syncthreads();
#pragma unroll 2
        for (int d = 0; d < 32; ++d) {
            float av[8];
            v2f bv2[2];
#pragma unroll
            for (int r = 0; r < 8; ++r) av[r] = sm.st.A[(rg + 16*r) * 33 + d];
            bv2[0].x = sm.st.B[(cb32     ) * 33 + d];
            bv2[0].y = sm.st.B[(cb32 + 32) * 33 + d];
            bv2[1].x = sm.st.B[(cb32 + 64) * 33 + d];
            bv2[1].y = sm.st.B[(cb32 + 96) * 33 + d];
#pragma unroll
            for (int r = 0; r < 8; ++r)
#pragma unroll
                for (int j = 0; j < 2; ++j)
                    lk2[r][j] += bv2[j] * av[r];   // v_pk_fma_f32
        }
        __syncthreads();
    }

    // logK2 = -M*log2e/eps, M = ||a||^2 + ||b||^2 - 2ab (clamped >= 0)
    float lb[4];
    const float lbv = flog2((float)n1) - flog2((float)n2);
    {
        float rn1[8];
        v2f rn2[2];
#pragma unroll
        for (int r = 0; r < 8; ++r) rn1[r] = sm.st.nA[rg + 16*r];
        rn2[0].x = sm.st.nB[cb32];      rn2[0].y = sm.st.nB[cb32 + 32];
        rn2[1].x = sm.st.nB[cb32 + 64]; rn2[1].y = sm.st.nB[cb32 + 96];
#pragma unroll
        for (int r = 0; r < 8; ++r)
#pragma unroll
            for (int j = 0; j < 2; ++j) {
                v2f M2 = rn1[r] + rn2[j] - 2.f * lk2[r][j];
                lk2[r][j].x = fmaxf(M2.x, 0.f) * LKSC;
                lk2[r][j].y = fmaxf(M2.y, 0.f) * LKSC;
            }
#pragma unroll
        for (int c = 0; c < 4; ++c)
            lb[c] = (cb32 + 32*c < n2) ? lbv : NEG2;
    }
    __syncthreads();   // retire staging view of the union

    const int   crow   = tid >> 2;                  // coop-combine row 0..127
    const int   q      = tid & 3;
    const float lacrow = (crow < n1) ? 0.f : NEG2;

    float uloc[8], v[4];
#pragma unroll
    for (int r = 0; r < 8; ++r) uloc[r] = 0.f;

    // ================= Phase 1: KLOG log-domain iterations =================
    for (int k = 0; k < KLOG; ++k) {
        float mx[4], sc[4];
#pragma unroll
        for (int c = 0; c < 4; ++c) mx[c] = LK(0, c) + uloc[0];
#pragma unroll
        for (int r = 1; r < 8; ++r)
#pragma unroll
            for (int c = 0; c < 4; ++c)
                mx[c] = fmaxf(mx[c], LK(r, c) + uloc[r]);
#pragma unroll
        for (int c = 0; c < 4; ++c) mx[c] = fmaxf(mx[c], dppf<DPP_ROR4>(mx[c]));
#pragma unroll
        for (int c = 0; c < 4; ++c) mx[c] = fmaxf(mx[c], dppf<DPP_ROR8>(mx[c]));
#pragma unroll
        for (int c = 0; c < 4; ++c) mx[c] = fmaxf(mx[c], swzx16(mx[c]));
#pragma unroll
        for (int c = 0; c < 4; ++c) mx[c] = fmaxf(mx[c], __shfl_xor(mx[c], 32));
#pragma unroll
        for (int c = 0; c < 4; ++c) sc[c] = fexp2(LK(0, c) + uloc[0] - mx[c]);
#pragma unroll
        for (int r = 1; r < 8; ++r)
#pragma unroll
            for (int c = 0; c < 4; ++c)
                sc[c] += fexp2(LK(r, c) + uloc[r] - mx[c]);
#pragma unroll
        for (int c = 0; c < 4; ++c) sc[c] += dppf<DPP_ROR4>(sc[c]);
#pragma unroll
        for (int c = 0; c < 4; ++c) sc[c] += dppf<DPP_ROR8>(sc[c]);
#pragma unroll
        for (int c = 0; c < 4; ++c) sc[c] += swzx16(sc[c]);
#pragma unroll
        for (int c = 0; c < 4; ++c) sc[c] += __shfl_xor(sc[c], 32);
#pragma unroll
        for (int c = 0; c < 4; ++c)
            v[c] = lb[c] - (mx[c] + flog2(sc[c]));

#pragma unroll
        for (int r = 0; r < 8; ++r) {
            float mr = LK(r, 0) + v[0];
#pragma unroll
            for (int c = 1; c < 4; ++c) mr = fmaxf(mr, LK(r, c) + v[c]);
            mr = fmaxf(mr, dppf<DPP_QX1>(mr));
            mr = fmaxf(mr, dppf<DPP_QX2>(mr));
            float sr = fexp2(LK(r, 0) + v[0] - mr);
#pragma unroll
            for (int c = 1; c < 4; ++c) sr += fexp2(LK(r, c) + v[c] - mr);
            sr += dppf<DPP_QX1>(sr);
            sr += dppf<DPP_QX2>(sr);
            if ((r & 3) == cg)
                sm.sk.plog[(rg + 16*r) * 10 + w] = make_float2(mr, sr);
        }
        __syncthreads();                               // B1

        {   // cooperative combine: 4 lanes per row fold 8 (m,s) partials
            float4 t = *(const float4*)&sm.sk.plog[crow * 10 + 2 * q];
            float m = fmaxf(t.x, t.z);
            float s = t.y * fexp2(t.x - m) + t.w * fexp2(t.z - m);
            float mo = dppf<DPP_QX1>(m), so = dppf<DPP_QX1>(s);
            float mm = fmaxf(m, mo);
            s = s * fexp2(m - mm) + so * fexp2(mo - mm); m = mm;
            mo = dppf<DPP_QX2>(m); so = dppf<DPP_QX2>(s);
            mm = fmaxf(m, mo);
            s = s * fexp2(m - mm) + so * fexp2(mo - mm); m = mm;
            if (q == 0) sm.sk.ulog[crow] = lacrow - (m + flog2(s));
        }
        __syncthreads();                               // B2

#pragma unroll
        for (int r = 0; r < 8; ++r) uloc[r] = sm.sk.ulog[rg + 16*r];
    }

    // ================= Phase 2 dispatch (block-uniform on n1) ==============
    const float bmulv = (float)n1 / (float)n2;   // beta for valid cols
    float fm[4];
#pragma unroll
    for (int c = 0; c < 4; ++c)
        fm[c] = (cb32 + 32*c < n2) ? bmulv : 0.f;
    const float gmask = (crow < n1) ? 1.f : 0.f;

    float acc;
    const int nr = (n1 + 15) >> 4;   // 4..8
    switch (nr) {
        case 4:  acc = sink_mul<4>(lk2, uloc, v, fm, gmask, sm, rg, cg, w, crow, q); break;
        case 5:  acc = sink_mul<5>(lk2, uloc, v, fm, gmask, sm, rg, cg, w, crow, q); break;
        case 6:  acc = sink_mul<6>(lk2, uloc, v, fm, gmask, sm, rg, cg, w, crow, q); break;
        case 7:  acc = sink_mul<7>(lk2, uloc, v, fm, gmask, sm, rg, cg, w, crow, q); break;
        default: acc = sink_mul<8>(lk2, uloc, v, fm, gmask, sm, rg, cg, w, crow, q); break;
    }

    // ---- output: out_b = OUTSC * block-sum(acc) ----
    acc += dppf<DPP_QX1>(acc);
    acc += dppf<DPP_QX2>(acc);
    acc += dppf<DPP_ROR4>(acc);
    acc += dppf<DPP_ROR8>(acc);
    acc += swzx16(acc);
    acc += __shfl_xor(acc, 32);
    if (lane == 0) swred[w] = acc;
    __syncthreads();
    if (tid == 0) {
        float s = 0.f;
#pragma unroll
        for (int i = 0; i < 8; ++i) s += swred[i];
        out[b] = s * OUTSC;
    }
}

extern "C" void kernel_launch(void* const* d_in, const int* in_sizes, int n_in,
                              void* d_out, int out_size, void* d_ws, size_t ws_size,
                              hipStream_t stream) {
    const float* x1  = (const float*)d_in[0];
    const float* x2  = (const float*)d_in[1];
    const int*   sz1 = (const int*)d_in[2];
    const int*   sz2 = (const int*)d_in[3];
    float* out = (float*)d_out;
    hipLaunchKernelGGL(wasserstein_kernel, dim3(512), dim3(512), 0, stream,
                       x1, x2, sz1, sz2, out);
}

// Round 6
// 622.961 us; speedup vs baseline: 1.2282x; 1.0261x over previous
//
#include <hip/hip_runtime.h>

#ifndef __has_builtin
#define __has_builtin(x) 0
#endif

typedef float v2f __attribute__((ext_vector_type(2)));

__device__ __forceinline__ float fexp2(float x) {
#if __has_builtin(__builtin_amdgcn_exp2f)
    return __builtin_amdgcn_exp2f(x);   // v_exp_f32 (2^x)
#else
    return exp2f(x);
#endif
}
__device__ __forceinline__ float flog2(float x) {
#if __has_builtin(__builtin_amdgcn_logf)
    return __builtin_amdgcn_logf(x);    // v_log_f32 (log2 x)
#else
    return log2f(x);
#endif
}
__device__ __forceinline__ float frcp(float x) {
#if __has_builtin(__builtin_amdgcn_rcpf)
    return __builtin_amdgcn_rcpf(x);    // v_rcp_f32 (approx; Sinkhorn self-corrects)
#else
    return 1.0f / x;
#endif
}

// ---- cross-lane helpers (round-1 proven set: DPP + ds_swizzle + shfl) -------
#define DPP_QX1  0xB1   // quad_perm [1,0,3,2] : lane ^ 1
#define DPP_QX2  0x4E   // quad_perm [2,3,0,1] : lane ^ 2
#define DPP_ROR4 0x124  // row_ror:4 (with ror8: sums full stride-4 class in 16)
#define DPP_ROR8 0x128  // row_ror:8

template<int CTRL>
__device__ __forceinline__ float dppf(float x) {
    return __int_as_float(__builtin_amdgcn_update_dpp(
        0, __float_as_int(x), CTRL, 0xF, 0xF, true));
}
// lane ^ 16 (ds_swizzle bitmode; xor stays within each 32-lane half)
__device__ __forceinline__ float swzx16(float x) {
    return __int_as_float(__builtin_amdgcn_ds_swizzle(__float_as_int(x), 0x401F));
}

#define NMAXN 128
#define DD    64
#define MAX_ITERS 500
#define KLOG  12            // log-domain warm-up iterations

// -1e5 * log2(e)  (NEG surrogate in log2 domain)
#define NEG2  (-144269.50408889634f)
// -(log2(e) / eps), eps = 1e-3 : logK2 = M * LKSC
#define LKSC  (-1442.6950408889634f)
// -(eps * ln2) : out = acc * OUTSC
#define OUTSC (-6.931471805599453e-4f)

// scalar view of the packed lk tile (c = 0..3 -> pair c>>1, half c&1)
#define LK(r, c) (((c) & 1) ? lk2[r][(c) >> 1].y : lk2[r][(c) >> 1].x)

struct SmemStage {
    float A[NMAXN * 33];   // set1 chunk [128][32] padded
    float B[NMAXN * 33];   // set2 chunk
    float nA[NMAXN];       // row norms set1
    float nB[NMAXN];       // row norms set2
};
struct SmemSink {
    float2 plog[NMAXN * 10];  // log-phase partials: [row*10+w] -> (max,sum)
    float  ulog[NMAXN];       // log-phase u
    float  pmul[NMAXN * 10];  // mul-phase row-sum partials: [row*10+w]
    float  g[NMAXN];          // mul-phase row factors
};
union SmemU {
    SmemStage st;
    SmemSink  sk;
    // occupancy clamp: 60 KiB -> exactly 2 blocks/CU; 512 blocks = 512 slots.
    char force[61440];
};

// ============== Load-balance prologue =======================================
// Work per pair ~ NR = ceil(n1/16). Blocks b and b+256 co-reside on a CU
// (in-order dispatch, round-robin over 8 XCDs x 32 CUs, 2 slots/CU). Place
// rank r (ascending n1) at position r for r<256 and 767-r for r>=256, so
// positions p and p+256 carry ranks r and 511-r -> per-CU work sums ~const.
__global__ __launch_bounds__(512, 1)
void balance_kernel(const int* __restrict__ sz1, int* __restrict__ perm)
{
    __shared__ int keys[512];
    const int tid = threadIdx.x;
    const int k = sz1[tid];
    keys[tid] = k;
    __syncthreads();
    int r = 0;
    for (int j = 0; j < 512; ++j) {           // same-address LDS reads: broadcast
        const int kj = keys[j];
        r += (int)((kj < k) | ((kj == k) & (j < tid)));
    }
    const int p = (r < 256) ? r : (767 - r);  // bijective: [0,255] U [256,511]
    perm[p] = tid;
}

// ================= Phase 2 (templated on NR = ceil(n1/16)) ==================
// Multiplicative Sinkhorn with lazy row factor g AND lazy column factor fc.
// Telescoping: fc_new = fc_old * (fm/(fc_old*S)) = fm/S, so the total pending
// column factor (since the last fold) is fm/S directly -- bounded, because S
// is the colsum of the recently-folded, plan-scale Q (round-1's empirical
// 16-iter drift bound). Both factors fold into Q every 16 iters.
// Rows r >= NR are exact zeros (u=NEG2 -> Q=0) and are skipped everywhere;
// their g comes from stale LDS but gmask=0 and the clamped rcp keep it 0.
template<int NR>
__device__ __forceinline__ float sink_mul(
    v2f (&lk2)[8][2], const float (&uloc)[8], const float (&v)[4],
    const float (&fm)[4], float gmask,
    SmemU& sm, int rg, int cg, int w, int crow, int q)
{
    // transition: Q = exp2(lk + u + v), constant between folds
    v2f Q2[NR][2];
#pragma unroll
    for (int r = 0; r < NR; ++r)
#pragma unroll
        for (int j = 0; j < 2; ++j) {
            Q2[r][j].x = fexp2(LK(r, 2*j    ) + uloc[r] + v[2*j    ]);
            Q2[r][j].y = fexp2(LK(r, 2*j + 1) + uloc[r] + v[2*j + 1]);
        }
    float gl[NR];
#pragma unroll
    for (int r = 0; r < NR; ++r) gl[r] = 1.f;
    v2f fc2[2];
    fc2[0].x = fc2[0].y = 0.f;
    fc2[1] = fc2[0];

    for (int k = KLOG; k < MAX_ITERS; ++k) {
        // --- col sums s_c = sum_r g_r Q_rc (2x2 independent fma chains) ---
        v2f p0 = Q2[0][0] * gl[0];
        v2f q0 = Q2[0][1] * gl[0];
        v2f p1; p1.x = 0.f; p1.y = 0.f;
        v2f q1 = p1;
        if constexpr (NR > 1) { p1 = Q2[1][0] * gl[1]; q1 = Q2[1][1] * gl[1]; }
#pragma unroll
        for (int r = 2; r < NR; ++r) {
            if ((r & 1) == 0) { p0 += Q2[r][0] * gl[r]; q0 += Q2[r][1] * gl[r]; }
            else              { p1 += Q2[r][0] * gl[r]; q1 += Q2[r][1] * gl[r]; }
        }
        v2f s20 = p0 + p1;
        v2f s21 = q0 + q1;
        float s[4] = { s20.x, s20.y, s21.x, s21.y };
#pragma unroll
        for (int c = 0; c < 4; ++c) s[c] += dppf<DPP_ROR4>(s[c]);
#pragma unroll
        for (int c = 0; c < 4; ++c) s[c] += dppf<DPP_ROR8>(s[c]);
#pragma unroll
        for (int c = 0; c < 4; ++c) s[c] += swzx16(s[c]);
#pragma unroll
        for (int c = 0; c < 4; ++c) s[c] += __shfl_xor(s[c], 32);
        // pending column factor = fm / S (total since last fold)
        fc2[0].x = fm[0] * frcp(fmaxf(s[0], 1e-37f));
        fc2[0].y = fm[1] * frcp(fmaxf(s[1], 1e-37f));
        fc2[1].x = fm[2] * frcp(fmaxf(s[2], 1e-37f));
        fc2[1].y = fm[3] * frcp(fmaxf(s[3], 1e-37f));

        // --- row sums t_r = sum_c Q_rc fc_c (Q read-only) ---
#pragma unroll
        for (int r = 0; r < NR; ++r) {
            v2f t2 = Q2[r][0] * fc2[0];
            t2 += Q2[r][1] * fc2[1];     // v_pk_fma_f32
            float t = t2.x + t2.y;
            t += dppf<DPP_QX1>(t);
            t += dppf<DPP_QX2>(t);
            if ((r & 3) == cg)
                sm.sk.pmul[(rg + 16*r) * 10 + w] = t;
        }
        __syncthreads();                               // B1

        {   // cooperative combine: 4 lanes per row fold 8 partials
            float2 t2r = *(const float2*)&sm.sk.pmul[crow * 10 + 2 * q];
            float t = t2r.x + t2r.y;
            t += dppf<DPP_QX1>(t);
            t += dppf<DPP_QX2>(t);
            float gg = gmask * frcp(fmaxf(t, 1e-37f));
            if (q == 0) sm.sk.g[crow] = gg;
        }
        __syncthreads();                               // B2

#pragma unroll
        for (int r = 0; r < NR; ++r) gl[r] = sm.sk.g[rg + 16*r];

        // fold both pending factors into Q (bounds drift; k=499 is NOT a fold
        // iteration with these constants, so epilogue factors stay pending)
        if ((k & 15) == 15) {
#pragma unroll
            for (int r = 0; r < NR; ++r) {
                Q2[r][0] *= fc2[0] * gl[r];
                Q2[r][1] *= fc2[1] * gl[r];
                gl[r] = 1.f;
            }
        }
    }

    // ---- epilogue accumulate: sum_ij lk_ij * (g_r Q_ij fc_c) ----
    v2f acc2; acc2.x = 0.f; acc2.y = 0.f;
#pragma unroll
    for (int r = 0; r < NR; ++r)
#pragma unroll
        for (int j = 0; j < 2; ++j)
            acc2 += lk2[r][j] * (Q2[r][j] * (fc2[j] * gl[r]));
    return acc2.x + acc2.y;
}

__global__ __launch_bounds__(512, 4)
void wasserstein_kernel(const float* __restrict__ x1, const float* __restrict__ x2,
                        const int* __restrict__ sz1, const int* __restrict__ sz2,
                        const int* __restrict__ perm,
                        float* __restrict__ out)
{
    __shared__ SmemU  sm;
    __shared__ int    soff[16];
    __shared__ float  swred[8];

    const int b    = perm[blockIdx.x];   // load-balanced pair assignment
    const int tid  = threadIdx.x;
    const int w    = tid >> 6;        // wave 0..7
    const int lane = tid & 63;
    const int rg   = lane >> 2;       // 0..15 : rows rg + 16*r   (r = 0..7)
    const int cg   = lane & 3;        // with w: cols (w*4+cg) + 32*c (c = 0..3)
    const int cb32 = (w << 2) | cg;   // 0..31

    // ---- exclusive prefix sums of sizes (512 threads: one element each) ----
    int a1 = (tid < b) ? sz1[tid] : 0;
    int a2 = (tid < b) ? sz2[tid] : 0;
#pragma unroll
    for (int d = 1; d < 64; d <<= 1) {
        a1 += __shfl_xor(a1, d);
        a2 += __shfl_xor(a2, d);
    }
    if (lane == 0) { soff[w] = a1; soff[8 + w] = a2; }
    if (tid < NMAXN) { sm.st.nA[tid] = 0.f; sm.st.nB[tid] = 0.f; }
    __syncthreads();
    int off1 = 0, off2 = 0;
#pragma unroll
    for (int i = 0; i < 8; ++i) { off1 += soff[i]; off2 += soff[8 + i]; }
    const int n1 = sz1[b];
    const int n2 = sz2[b];

    // ---- stage sets in D-chunks of 32, accumulate dots + norms ----
    v2f lk2[8][2];   // packed over col pairs; starts as dot acc, becomes logK2
#pragma unroll
    for (int r = 0; r < 8; ++r)
#pragma unroll
        for (int j = 0; j < 2; ++j) { lk2[r][j].x = 0.f; lk2[r][j].y = 0.f; }

    const int srow = tid >> 2;  // 0..127
    const int sq   = tid & 3;   // 8-float slice of the 32-col chunk

    for (int ch = 0; ch < 2; ++ch) {
        const float* p1 = x1 + (size_t)(off1 + srow) * DD + ch * 32 + sq * 8;
        const float* p2 = x2 + (size_t)(off2 + srow) * DD + ch * 32 + sq * 8;
        const bool ok1 = srow < n1;
        const bool ok2 = srow < n2;
        float va[8], vb[8];
#pragma unroll
        for (int qq = 0; qq < 2; ++qq) {
            float4 t1 = ok1 ? ((const float4*)p1)[qq] : make_float4(0.f, 0.f, 0.f, 0.f);
            float4 t2 = ok2 ? ((const float4*)p2)[qq] : make_float4(0.f, 0.f, 0.f, 0.f);
            va[4*qq+0] = t1.x; va[4*qq+1] = t1.y; va[4*qq+2] = t1.z; va[4*qq+3] = t1.w;
            vb[4*qq+0] = t2.x; vb[4*qq+1] = t2.y; vb[4*qq+2] = t2.z; vb[4*qq+3] = t2.w;
        }
        float s1 = 0.f, s2v = 0.f;
#pragma unroll
        for (int j = 0; j < 8; ++j) {
            sm.st.A[srow * 33 + sq * 8 + j] = va[j];
            sm.st.B[srow * 33 + sq * 8 + j] = vb[j];
            s1  += va[j] * va[j];
            s2v += vb[j] * vb[j];
        }
        s1  += dppf<DPP_QX1>(s1);  s1  += dppf<DPP_QX2>(s1);
        s2v += dppf<DPP_QX1>(s2v); s2v += dppf<DPP_QX2>(s2v);
        if (sq == 0) { sm.st.nA[srow] += s1; sm.st.nB[srow] += s2v; }
        __syncthreads();
#pragma unroll 2
        for (int d = 0; d < 32; ++d) {
            float av[8];
            v2f bv2[2];
#pragma unroll
            for (int r = 0; r < 8; ++r) av[r] = sm.st.A[(rg + 16*r) * 33 + d];
            bv2[0].x = sm.st.B[(cb32     ) * 33 + d];
            bv2[0].y = sm.st.B[(cb32 + 32) * 33 + d];
            bv2[1].x = sm.st.B[(cb32 + 64) * 33 + d];
            bv2[1].y = sm.st.B[(cb32 + 96) * 33 + d];
#pragma unroll
            for (int r = 0; r < 8; ++r)
#pragma unroll
                for (int j = 0; j < 2; ++j)
                    lk2[r][j] += bv2[j] * av[r];   // v_pk_fma_f32
        }
        __syncthreads();
    }

    // logK2 = -M*log2e/eps, M = ||a||^2 + ||b||^2 - 2ab (clamped >= 0)
    float lb[4];
    const float lbv = flog2((float)n1) - flog2((float)n2);
    {
        float rn1[8];
        v2f rn2[2];
#pragma unroll
        for (int r = 0; r < 8; ++r) rn1[r] = sm.st.nA[rg + 16*r];
        rn2[0].x = sm.st.nB[cb32];      rn2[0].y = sm.st.nB[cb32 + 32];
        rn2[1].x = sm.st.nB[cb32 + 64]; rn2[1].y = sm.st.nB[cb32 + 96];
#pragma unroll
        for (int r = 0; r < 8; ++r)
#pragma unroll
            for (int j = 0; j < 2; ++j) {
                v2f M2 = rn1[r] + rn2[j] - 2.f * lk2[r][j];
                lk2[r][j].x = fmaxf(M2.x, 0.f) * LKSC;
                lk2[r][j].y = fmaxf(M2.y, 0.f) * LKSC;
            }
#pragma unroll
        for (int c = 0; c < 4; ++c)
            lb[c] = (cb32 + 32*c < n2) ? lbv : NEG2;
    }
    __syncthreads();   // retire staging view of the union

    const int   crow   = tid >> 2;                  // coop-combine row 0..127
    const int   q      = tid & 3;
    const float lacrow = (crow < n1) ? 0.f : NEG2;

    float uloc[8], v[4];
#pragma unroll
    for (int r = 0; r < 8; ++r) uloc[r] = 0.f;

    // ================= Phase 1: KLOG log-domain iterations =================
    for (int k = 0; k < KLOG; ++k) {
        float mx[4], sc[4];
#pragma unroll
        for (int c = 0; c < 4; ++c) mx[c] = LK(0, c) + uloc[0];
#pragma unroll
        for (int r = 1; r < 8; ++r)
#pragma unroll
            for (int c = 0; c < 4; ++c)
                mx[c] = fmaxf(mx[c], LK(r, c) + uloc[r]);
#pragma unroll
        for (int c = 0; c < 4; ++c) mx[c] = fmaxf(mx[c], dppf<DPP_ROR4>(mx[c]));
#pragma unroll
        for (int c = 0; c < 4; ++c) mx[c] = fmaxf(mx[c], dppf<DPP_ROR8>(mx[c]));
#pragma unroll
        for (int c = 0; c < 4; ++c) mx[c] = fmaxf(mx[c], swzx16(mx[c]));
#pragma unroll
        for (int c = 0; c < 4; ++c) mx[c] = fmaxf(mx[c], __shfl_xor(mx[c], 32));
#pragma unroll
        for (int c = 0; c < 4; ++c) sc[c] = fexp2(LK(0, c) + uloc[0] - mx[c]);
#pragma unroll
        for (int r = 1; r < 8; ++r)
#pragma unroll
            for (int c = 0; c < 4; ++c)
                sc[c] += fexp2(LK(r, c) + uloc[r] - mx[c]);
#pragma unroll
        for (int c = 0; c < 4; ++c) sc[c] += dppf<DPP_ROR4>(sc[c]);
#pragma unroll
        for (int c = 0; c < 4; ++c) sc[c] += dppf<DPP_ROR8>(sc[c]);
#pragma unroll
        for (int c = 0; c < 4; ++c) sc[c] += swzx16(sc[c]);
#pragma unroll
        for (int c = 0; c < 4; ++c) sc[c] += __shfl_xor(sc[c], 32);
#pragma unroll
        for (int c = 0; c < 4; ++c)
            v[c] = lb[c] - (mx[c] + flog2(sc[c]));

#pragma unroll
        for (int r = 0; r < 8; ++r) {
            float mr = LK(r, 0) + v[0];
#pragma unroll
            for (int c = 1; c < 4; ++c) mr = fmaxf(mr, LK(r, c) + v[c]);
            mr = fmaxf(mr, dppf<DPP_QX1>(mr));
            mr = fmaxf(mr, dppf<DPP_QX2>(mr));
            float sr = fexp2(LK(r, 0) + v[0] - mr);
#pragma unroll
            for (int c = 1; c < 4; ++c) sr += fexp2(LK(r, c) + v[c] - mr);
            sr += dppf<DPP_QX1>(sr);
            sr += dppf<DPP_QX2>(sr);
            if ((r & 3) == cg)
                sm.sk.plog[(rg + 16*r) * 10 + w] = make_float2(mr, sr);
        }
        __syncthreads();                               // B1

        {   // cooperative combine: 4 lanes per row fold 8 (m,s) partials
            float4 t = *(const float4*)&sm.sk.plog[crow * 10 + 2 * q];
            float m = fmaxf(t.x, t.z);
            float s = t.y * fexp2(t.x - m) + t.w * fexp2(t.z - m);
            float mo = dppf<DPP_QX1>(m), so = dppf<DPP_QX1>(s);
            float mm = fmaxf(m, mo);
            s = s * fexp2(m - mm) + so * fexp2(mo - mm); m = mm;
            mo = dppf<DPP_QX2>(m); so = dppf<DPP_QX2>(s);
            mm = fmaxf(m, mo);
            s = s * fexp2(m - mm) + so * fexp2(mo - mm); m = mm;
            if (q == 0) sm.sk.ulog[crow] = lacrow - (m + flog2(s));
        }
        __syncthreads();                               // B2

#pragma unroll
        for (int r = 0; r < 8; ++r) uloc[r] = sm.sk.ulog[rg + 16*r];
    }

    // ================= Phase 2 dispatch (block-uniform on n1) ==============
    const float bmulv = (float)n1 / (float)n2;   // beta for valid cols
    float fm[4];
#pragma unroll
    for (int c = 0; c < 4; ++c)
        fm[c] = (cb32 + 32*c < n2) ? bmulv : 0.f;
    const float gmask = (crow < n1) ? 1.f : 0.f;

    float acc;
    const int nr = (n1 + 15) >> 4;   // 4..8
    switch (nr) {
        case 4:  acc = sink_mul<4>(lk2, uloc, v, fm, gmask, sm, rg, cg, w, crow, q); break;
        case 5:  acc = sink_mul<5>(lk2, uloc, v, fm, gmask, sm, rg, cg, w, crow, q); break;
        case 6:  acc = sink_mul<6>(lk2, uloc, v, fm, gmask, sm, rg, cg, w, crow, q); break;
        case 7:  acc = sink_mul<7>(lk2, uloc, v, fm, gmask, sm, rg, cg, w, crow, q); break;
        default: acc = sink_mul<8>(lk2, uloc, v, fm, gmask, sm, rg, cg, w, crow, q); break;
    }

    // ---- output: out_b = OUTSC * block-sum(acc) ----
    acc += dppf<DPP_QX1>(acc);
    acc += dppf<DPP_QX2>(acc);
    acc += dppf<DPP_ROR4>(acc);
    acc += dppf<DPP_ROR8>(acc);
    acc += swzx16(acc);
    acc += __shfl_xor(acc, 32);
    if (lane == 0) swred[w] = acc;
    __syncthreads();
    if (tid == 0) {
        float s = 0.f;
#pragma unroll
        for (int i = 0; i < 8; ++i) s += swred[i];
        out[b] = s * OUTSC;
    }
}

extern "C" void kernel_launch(void* const* d_in, const int* in_sizes, int n_in,
                              void* d_out, int out_size, void* d_ws, size_t ws_size,
                              hipStream_t stream) {
    const float* x1  = (const float*)d_in[0];
    const float* x2  = (const float*)d_in[1];
    const int*   sz1 = (const int*)d_in[2];
    const int*   sz2 = (const int*)d_in[3];
    float* out = (float*)d_out;
    int* perm = (int*)d_ws;   // 512 ints = 2 KiB of workspace

    hipLaunchKernelGGL(balance_kernel, dim3(1), dim3(512), 0, stream, sz1, perm);
    hipLaunchKernelGGL(wasserstein_kernel, dim3(512), dim3(512), 0, stream,
                       x1, x2, sz1, sz2, perm, out);
}

// Round 7
// 592.766 us; speedup vs baseline: 1.2907x; 1.0509x over previous
//
#include <hip/hip_runtime.h>

#ifndef __has_builtin
#define __has_builtin(x) 0
#endif

typedef float v2f __attribute__((ext_vector_type(2)));

__device__ __forceinline__ float fexp2(float x) {
#if __has_builtin(__builtin_amdgcn_exp2f)
    return __builtin_amdgcn_exp2f(x);   // v_exp_f32 (2^x)
#else
    return exp2f(x);
#endif
}
__device__ __forceinline__ float flog2(float x) {
#if __has_builtin(__builtin_amdgcn_logf)
    return __builtin_amdgcn_logf(x);    // v_log_f32 (log2 x)
#else
    return log2f(x);
#endif
}
__device__ __forceinline__ float frcp(float x) {
#if __has_builtin(__builtin_amdgcn_rcpf)
    return __builtin_amdgcn_rcpf(x);    // v_rcp_f32 (approx; Sinkhorn self-corrects)
#else
    return 1.0f / x;
#endif
}

// ---- cross-lane helpers (round-1 proven set: DPP + ds_swizzle + shfl) -------
#define DPP_QX1  0xB1   // quad_perm [1,0,3,2] : lane ^ 1
#define DPP_QX2  0x4E   // quad_perm [2,3,0,1] : lane ^ 2
#define DPP_ROR4 0x124  // row_ror:4 (with ror8: sums full stride-4 class in 16)
#define DPP_ROR8 0x128  // row_ror:8

template<int CTRL>
__device__ __forceinline__ float dppf(float x) {
    return __int_as_float(__builtin_amdgcn_update_dpp(
        0, __float_as_int(x), CTRL, 0xF, 0xF, true));
}
// lane ^ 16 (ds_swizzle bitmode; xor stays within each 32-lane half)
__device__ __forceinline__ float swzx16(float x) {
    return __int_as_float(__builtin_amdgcn_ds_swizzle(__float_as_int(x), 0x401F));
}

// 1-of-4 select by two loop-invariant lane predicates (3 v_cndmask)
__device__ __forceinline__ float sel4(float a0, float a1, float a2, float a3,
                                      bool c1, bool c2) {
    float x = c1 ? a1 : a0;
    float y = c1 ? a3 : a2;
    return c2 ? y : x;
}

#define NMAXN 128
#define DD    64
#define MAX_ITERS 500
#define KLOG  12            // log-domain warm-up iterations

// -1e5 * log2(e)  (NEG surrogate in log2 domain)
#define NEG2  (-144269.50408889634f)
// -(log2(e) / eps), eps = 1e-3 : logK2 = M * LKSC
#define LKSC  (-1442.6950408889634f)
// -(eps * ln2) : out = acc * OUTSC
#define OUTSC (-6.931471805599453e-4f)

// scalar view of the packed lk tile (c = 0..3 -> pair c>>1, half c&1)
#define LK(r, c) (((c) & 1) ? lk2[r][(c) >> 1].y : lk2[r][(c) >> 1].x)

struct SmemStage {
    float A[NMAXN * 33];   // set1 chunk [128][32] padded
    float B[NMAXN * 33];   // set2 chunk
    float nA[NMAXN];       // row norms set1
    float nB[NMAXN];       // row norms set2
};
struct SmemSink {
    float2 plog[NMAXN * 10];  // log-phase partials: [row*10+w] -> (max,sum)
    float  ulog[NMAXN];       // log-phase u
    float  pmul[NMAXN * 10];  // mul-phase row-sum partials: [row*10+w]
    float  g[NMAXN];          // mul-phase row factors
};
union SmemU {
    SmemStage st;
    SmemSink  sk;
    // occupancy clamp: 60 KiB -> exactly 2 blocks/CU; 512 blocks = 512 slots.
    char force[61440];
};

// ============== Load-balance prologue =======================================
// Work per pair ~ NR = ceil(n1/16). Blocks b and b+256 co-reside on a CU
// (in-order dispatch, round-robin over 8 XCDs x 32 CUs, 2 slots/CU). Place
// rank r (ascending n1) at position r for r<256 and 767-r for r>=256, so
// positions p and p+256 carry ranks r and 511-r -> per-CU work sums ~const.
__global__ __launch_bounds__(512, 1)
void balance_kernel(const int* __restrict__ sz1, int* __restrict__ perm)
{
    __shared__ int keys[512];
    const int tid = threadIdx.x;
    const int k = sz1[tid];
    keys[tid] = k;
    __syncthreads();
    int r = 0;
    for (int j = 0; j < 512; ++j) {           // same-address LDS reads: broadcast
        const int kj = keys[j];
        r += (int)((kj < k) | ((kj == k) & (j < tid)));
    }
    const int p = (r < 256) ? r : (767 - r);  // bijective: [0,255] U [256,511]
    perm[p] = tid;
}

// ================= Phase 2 (templated on NR = ceil(n1/16)) ==================
// Multiplicative Sinkhorn with lazy row factor g AND lazy column factor fc.
// Telescoping: fc_new = fc_old * (fm/(fc_old*S)) = fm/S, so the total pending
// column factor (since the last fold) is fm/S directly -- bounded, because S
// is the colsum of the recently-folded, plan-scale Q (round-1's empirical
// 16-iter drift bound). Both factors fold into Q every 16 iters.
// Rows r >= NR are exact zeros (u=NEG2 -> Q=0) and are skipped everywhere;
// their g comes from stale LDS but gmask=0 and the clamped rcp keep it 0.
// Row-partial stores: after the 2 quad-DPP adds, t is UNIFORM across each
// quad, so lane cg selects rows r=cg and r=cg+4 via sel4 (3 cndmask each)
// and does 2 unconditional stores -- replaces 8 exec-masked stores
// (~4 instr each: v_cmp + saveexec + ds_write + restore).
template<int NR>
__device__ __forceinline__ float sink_mul(
    v2f (&lk2)[8][2], const float (&uloc)[8], const float (&v)[4],
    const float (&fm)[4], float gmask,
    SmemU& sm, int rg, int cg, int w, int crow, int q)
{
    const bool c1 = (cg & 1) != 0;
    const bool c2 = (cg & 2) != 0;
    const int  pstoreL = (rg + 16 * cg) * 10 + w;   // row rg+16*cg
    const int  pstoreH = pstoreL + 640;             // row rg+16*cg+64 (*10)

    // transition: Q = exp2(lk + u + v), constant between folds
    v2f Q2[NR][2];
#pragma unroll
    for (int r = 0; r < NR; ++r)
#pragma unroll
        for (int j = 0; j < 2; ++j) {
            Q2[r][j].x = fexp2(LK(r, 2*j    ) + uloc[r] + v[2*j    ]);
            Q2[r][j].y = fexp2(LK(r, 2*j + 1) + uloc[r] + v[2*j + 1]);
        }
    float gl[NR];
#pragma unroll
    for (int r = 0; r < NR; ++r) gl[r] = 1.f;
    v2f fc2[2];
    fc2[0].x = fc2[0].y = 0.f;
    fc2[1] = fc2[0];

    for (int k = KLOG; k < MAX_ITERS; ++k) {
        // --- col sums s_c = sum_r g_r Q_rc (2x2 independent fma chains) ---
        v2f p0 = Q2[0][0] * gl[0];
        v2f q0 = Q2[0][1] * gl[0];
        v2f p1; p1.x = 0.f; p1.y = 0.f;
        v2f q1 = p1;
        if constexpr (NR > 1) { p1 = Q2[1][0] * gl[1]; q1 = Q2[1][1] * gl[1]; }
#pragma unroll
        for (int r = 2; r < NR; ++r) {
            if ((r & 1) == 0) { p0 += Q2[r][0] * gl[r]; q0 += Q2[r][1] * gl[r]; }
            else              { p1 += Q2[r][0] * gl[r]; q1 += Q2[r][1] * gl[r]; }
        }
        v2f s20 = p0 + p1;
        v2f s21 = q0 + q1;
        float s[4] = { s20.x, s20.y, s21.x, s21.y };
#pragma unroll
        for (int c = 0; c < 4; ++c) s[c] += dppf<DPP_ROR4>(s[c]);
#pragma unroll
        for (int c = 0; c < 4; ++c) s[c] += dppf<DPP_ROR8>(s[c]);
#pragma unroll
        for (int c = 0; c < 4; ++c) s[c] += swzx16(s[c]);
#pragma unroll
        for (int c = 0; c < 4; ++c) s[c] += __shfl_xor(s[c], 32);
        // pending column factor = fm / S (total since last fold)
        fc2[0].x = fm[0] * frcp(fmaxf(s[0], 1e-37f));
        fc2[0].y = fm[1] * frcp(fmaxf(s[1], 1e-37f));
        fc2[1].x = fm[2] * frcp(fmaxf(s[2], 1e-37f));
        fc2[1].y = fm[3] * frcp(fmaxf(s[3], 1e-37f));

        // --- row sums t_r = sum_c Q_rc fc_c (Q read-only) ---
        float tr[8];
#pragma unroll
        for (int r = 0; r < NR; ++r) {
            v2f t2 = Q2[r][0] * fc2[0];
            t2 += Q2[r][1] * fc2[1];     // v_pk_fma_f32
            float t = t2.x + t2.y;
            t += dppf<DPP_QX1>(t);
            t += dppf<DPP_QX2>(t);
            tr[r] = t;                   // uniform across the quad
        }
        {   // lane cg stores rows cg and cg+4 (2 unconditional-ish stores)
            float tlo = sel4(tr[0], tr[1], tr[2], tr[3], c1, c2);
            sm.sk.pmul[pstoreL] = tlo;
            if constexpr (NR > 4) {
                float thi = sel4(tr[4],
                                 (NR > 5) ? tr[5] : tr[4],
                                 (NR > 6) ? tr[6] : tr[4],
                                 (NR > 7) ? tr[7] : tr[4], c1, c2);
                if constexpr (NR == 8) {
                    sm.sk.pmul[pstoreH] = thi;
                } else {
                    if (cg < NR - 4) sm.sk.pmul[pstoreH] = thi;
                }
            }
        }
        __syncthreads();                               // B1

        {   // cooperative combine: 4 lanes per row fold 8 partials
            float2 t2r = *(const float2*)&sm.sk.pmul[crow * 10 + 2 * q];
            float t = t2r.x + t2r.y;
            t += dppf<DPP_QX1>(t);
            t += dppf<DPP_QX2>(t);
            float gg = gmask * frcp(fmaxf(t, 1e-37f));
            if (q == 0) sm.sk.g[crow] = gg;
        }
        __syncthreads();                               // B2

#pragma unroll
        for (int r = 0; r < NR; ++r) gl[r] = sm.sk.g[rg + 16*r];

        // fold both pending factors into Q (bounds drift; k=499 is NOT a fold
        // iteration with these constants, so epilogue factors stay pending)
        if ((k & 15) == 15) {
#pragma unroll
            for (int r = 0; r < NR; ++r) {
                Q2[r][0] *= fc2[0] * gl[r];
                Q2[r][1] *= fc2[1] * gl[r];
                gl[r] = 1.f;
            }
        }
    }

    // ---- epilogue accumulate: sum_ij lk_ij * (g_r Q_ij fc_c) ----
    v2f acc2; acc2.x = 0.f; acc2.y = 0.f;
#pragma unroll
    for (int r = 0; r < NR; ++r)
#pragma unroll
        for (int j = 0; j < 2; ++j)
            acc2 += lk2[r][j] * (Q2[r][j] * (fc2[j] * gl[r]));
    return acc2.x + acc2.y;
}

__global__ __launch_bounds__(512, 4)
void wasserstein_kernel(const float* __restrict__ x1, const float* __restrict__ x2,
                        const int* __restrict__ sz1, const int* __restrict__ sz2,
                        const int* __restrict__ perm,
                        float* __restrict__ out)
{
    __shared__ SmemU  sm;
    __shared__ int    soff[16];
    __shared__ float  swred[8];

    const int b    = perm[blockIdx.x];   // load-balanced pair assignment
    const int tid  = threadIdx.x;
    const int w    = tid >> 6;        // wave 0..7
    const int lane = tid & 63;
    const int rg   = lane >> 2;       // 0..15 : rows rg + 16*r   (r = 0..7)
    const int cg   = lane & 3;        // with w: cols (w*4+cg) + 32*c (c = 0..3)
    const int cb32 = (w << 2) | cg;   // 0..31

    // ---- exclusive prefix sums of sizes (512 threads: one element each) ----
    int a1 = (tid < b) ? sz1[tid] : 0;
    int a2 = (tid < b) ? sz2[tid] : 0;
#pragma unroll
    for (int d = 1; d < 64; d <<= 1) {
        a1 += __shfl_xor(a1, d);
        a2 += __shfl_xor(a2, d);
    }
    if (lane == 0) { soff[w] = a1; soff[8 + w] = a2; }
    if (tid < NMAXN) { sm.st.nA[tid] = 0.f; sm.st.nB[tid] = 0.f; }
    __syncthreads();
    int off1 = 0, off2 = 0;
#pragma unroll
    for (int i = 0; i < 8; ++i) { off1 += soff[i]; off2 += soff[8 + i]; }
    const int n1 = sz1[b];
    const int n2 = sz2[b];

    // ---- stage sets in D-chunks of 32, accumulate dots + norms ----
    v2f lk2[8][2];   // packed over col pairs; starts as dot acc, becomes logK2
#pragma unroll
    for (int r = 0; r < 8; ++r)
#pragma unroll
        for (int j = 0; j < 2; ++j) { lk2[r][j].x = 0.f; lk2[r][j].y = 0.f; }

    const int srow = tid >> 2;  // 0..127
    const int sq   = tid & 3;   // 8-float slice of the 32-col chunk

    for (int ch = 0; ch < 2; ++ch) {
        const float* p1 = x1 + (size_t)(off1 + srow) * DD + ch * 32 + sq * 8;
        const float* p2 = x2 + (size_t)(off2 + srow) * DD + ch * 32 + sq * 8;
        const bool ok1 = srow < n1;
        const bool ok2 = srow < n2;
        float va[8], vb[8];
#pragma unroll
        for (int qq = 0; qq < 2; ++qq) {
            float4 t1 = ok1 ? ((const float4*)p1)[qq] : make_float4(0.f, 0.f, 0.f, 0.f);
            float4 t2 = ok2 ? ((const float4*)p2)[qq] : make_float4(0.f, 0.f, 0.f, 0.f);
            va[4*qq+0] = t1.x; va[4*qq+1] = t1.y; va[4*qq+2] = t1.z; va[4*qq+3] = t1.w;
            vb[4*qq+0] = t2.x; vb[4*qq+1] = t2.y; vb[4*qq+2] = t2.z; vb[4*qq+3] = t2.w;
        }
        float s1 = 0.f, s2v = 0.f;
#pragma unroll
        for (int j = 0; j < 8; ++j) {
            sm.st.A[srow * 33 + sq * 8 + j] = va[j];
            sm.st.B[srow * 33 + sq * 8 + j] = vb[j];
            s1  += va[j] * va[j];
            s2v += vb[j] * vb[j];
        }
        s1  += dppf<DPP_QX1>(s1);  s1  += dppf<DPP_QX2>(s1);
        s2v += dppf<DPP_QX1>(s2v); s2v += dppf<DPP_QX2>(s2v);
        if (sq == 0) { sm.st.nA[srow] += s1; sm.st.nB[srow] += s2v; }
        __syncthreads();
#pragma unroll 2
        for (int d = 0; d < 32; ++d) {
            float av[8];
            v2f bv2[2];
#pragma unroll
            for (int r = 0; r < 8; ++r) av[r] = sm.st.A[(rg + 16*r) * 33 + d];
            bv2[0].x = sm.st.B[(cb32     ) * 33 + d];
            bv2[0].y = sm.st.B[(cb32 + 32) * 33 + d];
            bv2[1].x = sm.st.B[(cb32 + 64) * 33 + d];
            bv2[1].y = sm.st.B[(cb32 + 96) * 33 + d];
#pragma unroll
            for (int r = 0; r < 8; ++r)
#pragma unroll
                for (int j = 0; j < 2; ++j)
                    lk2[r][j] += bv2[j] * av[r];   // v_pk_fma_f32
        }
        __syncthreads();
    }

    // logK2 = -M*log2e/eps, M = ||a||^2 + ||b||^2 - 2ab (clamped >= 0)
    float lb[4];
    const float lbv = flog2((float)n1) - flog2((float)n2);
    {
        float rn1[8];
        v2f rn2[2];
#pragma unroll
        for (int r = 0; r < 8; ++r) rn1[r] = sm.st.nA[rg + 16*r];
        rn2[0].x = sm.st.nB[cb32];      rn2[0].y = sm.st.nB[cb32 + 32];
        rn2[1].x = sm.st.nB[cb32 + 64]; rn2[1].y = sm.st.nB[cb32 + 96];
#pragma unroll
        for (int r = 0; r < 8; ++r)
#pragma unroll
            for (int j = 0; j < 2; ++j) {
                v2f M2 = rn1[r] + rn2[j] - 2.f * lk2[r][j];
                lk2[r][j].x = fmaxf(M2.x, 0.f) * LKSC;
                lk2[r][j].y = fmaxf(M2.y, 0.f) * LKSC;
            }
#pragma unroll
        for (int c = 0; c < 4; ++c)
            lb[c] = (cb32 + 32*c < n2) ? lbv : NEG2;
    }
    __syncthreads();   // retire staging view of the union

    const int   crow   = tid >> 2;                  // coop-combine row 0..127
    const int   q      = tid & 3;
    const float lacrow = (crow < n1) ? 0.f : NEG2;

    float uloc[8], v[4];
#pragma unroll
    for (int r = 0; r < 8; ++r) uloc[r] = 0.f;

    // ================= Phase 1: KLOG log-domain iterations =================
    for (int k = 0; k < KLOG; ++k) {
        float mx[4], sc[4];
#pragma unroll
        for (int c = 0; c < 4; ++c) mx[c] = LK(0, c) + uloc[0];
#pragma unroll
        for (int r = 1; r < 8; ++r)
#pragma unroll
            for (int c = 0; c < 4; ++c)
                mx[c] = fmaxf(mx[c], LK(r, c) + uloc[r]);
#pragma unroll
        for (int c = 0; c < 4; ++c) mx[c] = fmaxf(mx[c], dppf<DPP_ROR4>(mx[c]));
#pragma unroll
        for (int c = 0; c < 4; ++c) mx[c] = fmaxf(mx[c], dppf<DPP_ROR8>(mx[c]));
#pragma unroll
        for (int c = 0; c < 4; ++c) mx[c] = fmaxf(mx[c], swzx16(mx[c]));
#pragma unroll
        for (int c = 0; c < 4; ++c) mx[c] = fmaxf(mx[c], __shfl_xor(mx[c], 32));
#pragma unroll
        for (int c = 0; c < 4; ++c) sc[c] = fexp2(LK(0, c) + uloc[0] - mx[c]);
#pragma unroll
        for (int r = 1; r < 8; ++r)
#pragma unroll
            for (int c = 0; c < 4; ++c)
                sc[c] += fexp2(LK(r, c) + uloc[r] - mx[c]);
#pragma unroll
        for (int c = 0; c < 4; ++c) sc[c] += dppf<DPP_ROR4>(sc[c]);
#pragma unroll
        for (int c = 0; c < 4; ++c) sc[c] += dppf<DPP_ROR8>(sc[c]);
#pragma unroll
        for (int c = 0; c < 4; ++c) sc[c] += swzx16(sc[c]);
#pragma unroll
        for (int c = 0; c < 4; ++c) sc[c] += __shfl_xor(sc[c], 32);
#pragma unroll
        for (int c = 0; c < 4; ++c)
            v[c] = lb[c] - (mx[c] + flog2(sc[c]));

#pragma unroll
        for (int r = 0; r < 8; ++r) {
            float mr = LK(r, 0) + v[0];
#pragma unroll
            for (int c = 1; c < 4; ++c) mr = fmaxf(mr, LK(r, c) + v[c]);
            mr = fmaxf(mr, dppf<DPP_QX1>(mr));
            mr = fmaxf(mr, dppf<DPP_QX2>(mr));
            float sr = fexp2(LK(r, 0) + v[0] - mr);
#pragma unroll
            for (int c = 1; c < 4; ++c) sr += fexp2(LK(r, c) + v[c] - mr);
            sr += dppf<DPP_QX1>(sr);
            sr += dppf<DPP_QX2>(sr);
            if ((r & 3) == cg)
                sm.sk.plog[(rg + 16*r) * 10 + w] = make_float2(mr, sr);
        }
        __syncthreads();                               // B1

        {   // cooperative combine: 4 lanes per row fold 8 (m,s) partials
            float4 t = *(const float4*)&sm.sk.plog[crow * 10 + 2 * q];
            float m = fmaxf(t.x, t.z);
            float s = t.y * fexp2(t.x - m) + t.w * fexp2(t.z - m);
            float mo = dppf<DPP_QX1>(m), so = dppf<DPP_QX1>(s);
            float mm = fmaxf(m, mo);
            s = s * fexp2(m - mm) + so * fexp2(mo - mm); m = mm;
            mo = dppf<DPP_QX2>(m); so = dppf<DPP_QX2>(s);
            mm = fmaxf(m, mo);
            s = s * fexp2(m - mm) + so * fexp2(mo - mm); m = mm;
            if (q == 0) sm.sk.ulog[crow] = lacrow - (m + flog2(s));
        }
        __syncthreads();                               // B2

#pragma unroll
        for (int r = 0; r < 8; ++r) uloc[r] = sm.sk.ulog[rg + 16*r];
    }

    // ================= Phase 2 dispatch (block-uniform on n1) ==============
    const float bmulv = (float)n1 / (float)n2;   // beta for valid cols
    float fm[4];
#pragma unroll
    for (int c = 0; c < 4; ++c)
        fm[c] = (cb32 + 32*c < n2) ? bmulv : 0.f;
    const float gmask = (crow < n1) ? 1.f : 0.f;

    float acc;
    const int nr = (n1 + 15) >> 4;   // 4..8
    switch (nr) {
        case 4:  acc = sink_mul<4>(lk2, uloc, v, fm, gmask, sm, rg, cg, w, crow, q); break;
        case 5:  acc = sink_mul<5>(lk2, uloc, v, fm, gmask, sm, rg, cg, w, crow, q); break;
        case 6:  acc = sink_mul<6>(lk2, uloc, v, fm, gmask, sm, rg, cg, w, crow, q); break;
        case 7:  acc = sink_mul<7>(lk2, uloc, v, fm, gmask, sm, rg, cg, w, crow, q); break;
        default: acc = sink_mul<8>(lk2, uloc, v, fm, gmask, sm, rg, cg, w, crow, q); break;
    }

    // ---- output: out_b = OUTSC * block-sum(acc) ----
    acc += dppf<DPP_QX1>(acc);
    acc += dppf<DPP_QX2>(acc);
    acc += dppf<DPP_ROR4>(acc);
    acc += dppf<DPP_ROR8>(acc);
    acc += swzx16(acc);
    acc += __shfl_xor(acc, 32);
    if (lane == 0) swred[w] = acc;
    __syncthreads();
    if (tid == 0) {
        float s = 0.f;
#pragma unroll
        for (int i = 0; i < 8; ++i) s += swred[i];
        out[b] = s * OUTSC;
    }
}

extern "C" void kernel_launch(void* const* d_in, const int* in_sizes, int n_in,
                              void* d_out, int out_size, void* d_ws, size_t ws_size,
                              hipStream_t stream) {
    const float* x1  = (const float*)d_in[0];
    const float* x2  = (const float*)d_in[1];
    const int*   sz1 = (const int*)d_in[2];
    const int*   sz2 = (const int*)d_in[3];
    float* out = (float*)d_out;
    int* perm = (int*)d_ws;   // 512 ints = 2 KiB of workspace

    hipLaunchKernelGGL(balance_kernel, dim3(1), dim3(512), 0, stream, sz1, perm);
    hipLaunchKernelGGL(wasserstein_kernel, dim3(512), dim3(512), 0, stream,
                       x1, x2, sz1, sz2, perm, out);
}